// Round 1
// baseline (612.137 us; speedup 1.0000x reference)
//
#include <hip/hip_runtime.h>
#include <hip/hip_bf16.h>
#include <math.h>

#define H 120
#define W 216
#define C 256
#define NPIX (H*W)
#define PATCH 13
#define PP 169
#define RAD 6
#define TOPKN 36
#define OBJ 11
#define MD 4
#define CW 344   // padded corr row stride (338 -> 344)
#define CCH 4    // channel chunk
#define TW 64    // tile width (pixels per block, 1 row)

// ---------------- kernel 1: mask downsample (::4,::4) ----------------
__global__ void k_downsample(const float* __restrict__ m0, const float* __restrict__ m1,
                             float* __restrict__ mds) {
  int i = blockIdx.x * 256 + threadIdx.x;
  const int total = 2 * OBJ * NPIX;
  if (i >= total) return;
  int fo = i / NPIX;
  int pix = i - fo * NPIX;
  int f = fo / OBJ, o = fo - f * OBJ;
  int y = pix / W, x = pix - y * W;
  const float* src = f ? m1 : m0;
  mds[i] = src[(size_t)o * (H*MD) * (W*MD) + (size_t)(MD*y) * (W*MD) + MD*x];
}

// ---------------- kernel 2: local correlation volume ----------------
// grid: (ceil(W/TW), H, 2 frames); block 256.
// thread: xg = t&15 -> 4 consecutive x; og = t>>4 -> di (og<13 active).
__global__ __launch_bounds__(256) void k_corr(const float* __restrict__ fq,
                       const float* __restrict__ fm0, const float* __restrict__ fm1,
                       float* __restrict__ corr) {
  const int x0 = blockIdx.x * TW;
  const int y  = blockIdx.y;
  const int f  = blockIdx.z;
  const float* fm = f ? fm1 : fm0;
  const int t  = threadIdx.x;
  const int xg = t & 15;
  const int og = t >> 4;

  __shared__ float fm_s[CCH * PATCH * 76];
  __shared__ float fq_s[CCH * TW];

  float4 acc[PATCH];
  #pragma unroll
  for (int d = 0; d < PATCH; ++d) acc[d] = make_float4(0.f, 0.f, 0.f, 0.f);

  for (int c0 = 0; c0 < C; c0 += CCH) {
    // stage fm window [CCH][13][76] with zero-pad
    for (int i = t; i < CCH * PATCH * 76; i += 256) {
      int c = i / (PATCH * 76);
      int rem = i - c * (PATCH * 76);
      int di = rem / 76;
      int col = rem - di * 76;
      int yy = y + di - RAD;
      int xx = x0 - RAD + col;
      float v = 0.f;
      if (yy >= 0 && yy < H && xx >= 0 && xx < W)
        v = fm[(size_t)(c0 + c) * NPIX + yy * W + xx];
      fm_s[i] = v;
    }
    { // stage fq [CCH][64]: exactly one elem per thread
      int c = t >> 6, j = t & 63;
      int xx = x0 + j;
      fq_s[t] = (xx < W) ? fq[(size_t)(c0 + c) * NPIX + y * W + xx] : 0.f;
    }
    __syncthreads();
    if (og < PATCH) {
      #pragma unroll
      for (int c = 0; c < CCH; ++c) {
        const float* fr = &fm_s[c * (PATCH * 76) + og * 76 + 4 * xg];
        float r[16];
        #pragma unroll
        for (int q = 0; q < 4; ++q) {
          float4 t4 = *(const float4*)(fr + 4 * q);
          r[4*q+0] = t4.x; r[4*q+1] = t4.y; r[4*q+2] = t4.z; r[4*q+3] = t4.w;
        }
        float4 q4 = *(const float4*)(&fq_s[c * TW + 4 * xg]);
        #pragma unroll
        for (int dj = 0; dj < PATCH; ++dj) {
          acc[dj].x += q4.x * r[dj + 0];
          acc[dj].y += q4.y * r[dj + 1];
          acc[dj].z += q4.z * r[dj + 2];
          acc[dj].w += q4.w * r[dj + 3];
        }
      }
    }
    __syncthreads();
  }

  if (og < PATCH) {
    #pragma unroll
    for (int dj = 0; dj < PATCH; ++dj) {
      float vv[4] = {acc[dj].x, acc[dj].y, acc[dj].z, acc[dj].w};
      #pragma unroll
      for (int p = 0; p < 4; ++p) {
        int x = x0 + 4 * xg + p;
        if (x < W) {
          int pix = y * W + x;
          int row = f * PP + og * PATCH + dj;
          corr[(size_t)pix * CW + row] = vv[p] * 0.0625f;  // /sqrt(256)
        }
      }
    }
  }
}

// ---------------- kernel 3: per-pixel top-36 + softmax + mask gather ----------------
// one wave (64 lanes) per pixel
__global__ __launch_bounds__(256) void k_topk(const float* __restrict__ corr,
                       const float* __restrict__ mds, float* __restrict__ out) {
  int wid = (blockIdx.x * 256 + threadIdx.x) >> 6;
  int lane = threadIdx.x & 63;
  if (wid >= NPIX) return;
  const float* cr = corr + (size_t)wid * CW;

  float v[6];
  #pragma unroll
  for (int s = 0; s < 6; ++s) {
    int idx = lane + 64 * s;
    v[s] = (idx < 2 * PP) ? cr[idx] : -INFINITY;
  }

  float m = 0.f, sum = 0.f, my_w = 0.f;
  int my_idx = 0;
  for (int k = 0; k < TOPKN; ++k) {
    // local argmax over 6 slots (earliest slot wins ties -> lowest index)
    float bv = v[0]; int bs = 0;
    #pragma unroll
    for (int q = 1; q < 6; ++q) { if (v[q] > bv) { bv = v[q]; bs = q; } }
    int bidx = lane + 64 * bs;
    // wave argmax, tie-break lower index (matches jax.lax.top_k)
    #pragma unroll
    for (int off = 32; off >= 1; off >>= 1) {
      float ov = __shfl_xor(bv, off, 64);
      int   oi = __shfl_xor(bidx, off, 64);
      if (ov > bv || (ov == bv && oi < bidx)) { bv = ov; bidx = oi; }
    }
    if (k == 0) m = bv;
    float wv = __expf(bv - m);
    sum += wv;
    if (lane == k) { my_w = wv; my_idx = bidx; }
    // eliminate winner
    if ((bidx & 63) == lane) {
      int s = bidx >> 6;
      #pragma unroll
      for (int q = 0; q < 6; ++q) { if (s == q) v[q] = -INFINITY; }
    }
  }

  int y = wid / W, x = wid - (wid / W) * W;
  float part[OBJ];
  #pragma unroll
  for (int o = 0; o < OBJ; ++o) part[o] = 0.f;
  if (lane < TOPKN) {
    int idx = my_idx;
    int f = (idx >= PP) ? 1 : 0;
    int r = idx - f * PP;
    int di = r / PATCH, dj = r - (r / PATCH) * PATCH;
    int yy = y + di - RAD, xx = x + dj - RAD;
    if (yy >= 0 && yy < H && xx >= 0 && xx < W) {
      const float* mb = mds + ((size_t)f * OBJ) * NPIX + yy * W + xx;
      #pragma unroll
      for (int o = 0; o < OBJ; ++o) part[o] = my_w * mb[(size_t)o * NPIX];
    }
  }
  float inv = 1.f / sum;
  #pragma unroll
  for (int o = 0; o < OBJ; ++o) {
    float p = part[o];
    #pragma unroll
    for (int off = 32; off >= 1; off >>= 1) p += __shfl_xor(p, off, 64);
    if (lane == 0) out[(size_t)o * NPIX + wid] = p * inv;
  }
}

extern "C" void kernel_launch(void* const* d_in, const int* in_sizes, int n_in,
                              void* d_out, int out_size, void* d_ws, size_t ws_size,
                              hipStream_t stream) {
  const float* fq  = (const float*)d_in[0];
  const float* fm0 = (const float*)d_in[1];
  const float* fm1 = (const float*)d_in[2];
  const float* m0  = (const float*)d_in[3];
  const float* m1  = (const float*)d_in[4];
  float* out = (float*)d_out;

  char* ws = (char*)d_ws;
  float* mds  = (float*)ws;
  size_t mds_bytes = (size_t)2 * OBJ * NPIX * sizeof(float);
  float* corr = (float*)(ws + ((mds_bytes + 1023) / 1024) * 1024);

  k_downsample<<<(2 * OBJ * NPIX + 255) / 256, 256, 0, stream>>>(m0, m1, mds);

  dim3 g2((W + TW - 1) / TW, H, 2);
  k_corr<<<g2, 256, 0, stream>>>(fq, fm0, fm1, corr);

  k_topk<<<NPIX / 4, 256, 0, stream>>>(corr, mds, out);
}

// Round 2
// 306.034 us; speedup vs baseline: 2.0002x; 2.0002x over previous
//
#include <hip/hip_runtime.h>
#include <hip/hip_bf16.h>
#include <math.h>

#define H 120
#define W 216
#define C 256
#define NPIX (H*W)
#define PATCH 13
#define PP 169
#define RAD 6
#define TOPKN 36
#define OBJ 11
#define MD 4
#define CW 344   // padded corr row stride (338 -> 344)

// ---------------- kernel 1: mask downsample (::4,::4) ----------------
__global__ void k_downsample(const float* __restrict__ m0, const float* __restrict__ m1,
                             float* __restrict__ mds) {
  int i = blockIdx.x * 256 + threadIdx.x;
  const int total = 2 * OBJ * NPIX;
  if (i >= total) return;
  int fo = i / NPIX;
  int pix = i - fo * NPIX;
  int f = fo / OBJ, o = fo - f * OBJ;
  int y = pix / W, x = pix - y * W;
  const float* src = f ? m1 : m0;
  mds[i] = src[(size_t)o * (H*MD) * (W*MD) + (size_t)(MD*y) * (W*MD) + MD*x];
}

// ---------------- kernel 2: local correlation, one (y, di, f) row per wave ----------------
// grid 3120 blocks x 64 threads. Thread xg owns 4 consecutive x, all 13 dj.
// fm row staged in LDS as [4 ch][232] (cols = x in [-8, 224), f4-aligned, zero-padded).
// fq read direct from global (coalesced float4, L1/L2).
// Accumulation order per output: c = 0..255 sequential fmac -> bit-identical to R0 baseline.
__global__ __launch_bounds__(64) void k_corr(const float* __restrict__ fq,
                       const float* __restrict__ fm0, const float* __restrict__ fm1,
                       float* __restrict__ corr) {
  // XCD-aware swizzle: 3120 = 8 * 390; give each XCD a contiguous y-range.
  int b = blockIdx.x;
  int lb = (b & 7) * 390 + (b >> 3);
  int y   = lb / 26;
  int r26 = lb - y * 26;
  int f   = r26 / 13;
  int di  = r26 - f * 13;
  const int tid = threadIdx.x;
  const int xg  = tid;            // xg < 54 active for compute
  const int r   = y + di - RAD;   // fm source row

  float* corr_base = corr + (size_t)(y * W) * CW + (f * PP + di * PATCH);

  if (r < 0 || r >= H) {
    // entire slice is zero (reference zero-pads fm)
    if (xg < 54) {
      float* cp = corr_base + (size_t)(4 * xg) * CW;
      #pragma unroll
      for (int sub = 0; sub < 4; ++sub) {
        #pragma unroll
        for (int dj = 0; dj < PATCH; ++dj) cp[(size_t)sub * CW + dj] = 0.f;
      }
    }
    return;
  }

  const float* fm = f ? fm1 : fm0;

  __shared__ float fm_s[4 * 232];   // 4 channels x 232 cols (x in [-8, 224))

  // precompute this thread's staging slots (fixed across channel chunks)
  // total f4 slots per chunk: 4 ch * 58 = 232; thread handles slots tid, tid+64, tid+128, tid+192
  const float* pf[4];
  int  ldsoff[4];
  bool sval[4];   // slot exists (i < 232)
  bool mval[4];   // f4 is in-bounds (else stage zeros)
  #pragma unroll
  for (int s = 0; s < 4; ++s) {
    int i = tid + 64 * s;
    sval[s] = (i < 232);
    int ii = sval[s] ? i : 0;
    int ch = ii / 58;
    int m  = ii - ch * 58;
    int x  = 4 * m - 8;
    mval[s] = sval[s] && (m >= 2) && (m <= 55);
    ldsoff[s] = ch * 232 + 4 * m;
    pf[s] = fm + (size_t)ch * NPIX + (size_t)r * W + (mval[s] ? x : 0);
  }

  const float* pq = fq + (size_t)y * W + 4 * xg;   // valid for xg<54; harmless otherwise
  if (xg >= 54) pq = fq;                            // keep loads in-bounds for idle lanes

  float4 acc[PATCH];
  #pragma unroll
  for (int d = 0; d < PATCH; ++d) acc[d] = make_float4(0.f, 0.f, 0.f, 0.f);

  for (int c0 = 0; c0 < C; c0 += 4) {
    // ---- stage fm row chunk [4][232] with vector loads ----
    #pragma unroll
    for (int s = 0; s < 4; ++s) {
      if (sval[s]) {
        float4 v = make_float4(0.f, 0.f, 0.f, 0.f);
        if (mval[s]) v = *(const float4*)(pf[s]);
        *(float4*)&fm_s[ldsoff[s]] = v;
        pf[s] += 4 * (size_t)NPIX;
      }
    }
    __syncthreads();

    if (xg < 54) {
      #pragma unroll
      for (int ch = 0; ch < 4; ++ch) {
        float4 q4 = *(const float4*)(pq + (size_t)ch * NPIX);
        float rr[20];
        #pragma unroll
        for (int q = 0; q < 5; ++q) {
          float4 t4 = *(const float4*)&fm_s[ch * 232 + 4 * xg + 4 * q];
          rr[4*q+0] = t4.x; rr[4*q+1] = t4.y; rr[4*q+2] = t4.z; rr[4*q+3] = t4.w;
        }
        #pragma unroll
        for (int dj = 0; dj < PATCH; ++dj) {
          acc[dj].x += q4.x * rr[dj + 2];
          acc[dj].y += q4.y * rr[dj + 3];
          acc[dj].z += q4.z * rr[dj + 4];
          acc[dj].w += q4.w * rr[dj + 5];
        }
      }
      pq += 4 * (size_t)NPIX;
    }
    __syncthreads();
  }

  if (xg < 54) {
    float* cp = corr_base + (size_t)(4 * xg) * CW;
    #pragma unroll
    for (int dj = 0; dj < PATCH; ++dj) {
      cp[dj]                    = acc[dj].x * 0.0625f;
      cp[(size_t)1 * CW + dj]   = acc[dj].y * 0.0625f;
      cp[(size_t)2 * CW + dj]   = acc[dj].z * 0.0625f;
      cp[(size_t)3 * CW + dj]   = acc[dj].w * 0.0625f;
    }
  }
}

// ---------------- kernel 3: per-pixel top-36 + softmax + mask gather ----------------
// one wave (64 lanes) per pixel  (unchanged from R0 — validated)
__global__ __launch_bounds__(256) void k_topk(const float* __restrict__ corr,
                       const float* __restrict__ mds, float* __restrict__ out) {
  int wid = (blockIdx.x * 256 + threadIdx.x) >> 6;
  int lane = threadIdx.x & 63;
  if (wid >= NPIX) return;
  const float* cr = corr + (size_t)wid * CW;

  float v[6];
  #pragma unroll
  for (int s = 0; s < 6; ++s) {
    int idx = lane + 64 * s;
    v[s] = (idx < 2 * PP) ? cr[idx] : -INFINITY;
  }

  float m = 0.f, sum = 0.f, my_w = 0.f;
  int my_idx = 0;
  for (int k = 0; k < TOPKN; ++k) {
    float bv = v[0]; int bs = 0;
    #pragma unroll
    for (int q = 1; q < 6; ++q) { if (v[q] > bv) { bv = v[q]; bs = q; } }
    int bidx = lane + 64 * bs;
    #pragma unroll
    for (int off = 32; off >= 1; off >>= 1) {
      float ov = __shfl_xor(bv, off, 64);
      int   oi = __shfl_xor(bidx, off, 64);
      if (ov > bv || (ov == bv && oi < bidx)) { bv = ov; bidx = oi; }
    }
    if (k == 0) m = bv;
    float wv = __expf(bv - m);
    sum += wv;
    if (lane == k) { my_w = wv; my_idx = bidx; }
    if ((bidx & 63) == lane) {
      int s = bidx >> 6;
      #pragma unroll
      for (int q = 0; q < 6; ++q) { if (s == q) v[q] = -INFINITY; }
    }
  }

  int y = wid / W, x = wid - (wid / W) * W;
  float part[OBJ];
  #pragma unroll
  for (int o = 0; o < OBJ; ++o) part[o] = 0.f;
  if (lane < TOPKN) {
    int idx = my_idx;
    int f = (idx >= PP) ? 1 : 0;
    int rr = idx - f * PP;
    int di = rr / PATCH, dj = rr - (rr / PATCH) * PATCH;
    int yy = y + di - RAD, xx = x + dj - RAD;
    if (yy >= 0 && yy < H && xx >= 0 && xx < W) {
      const float* mb = mds + ((size_t)f * OBJ) * NPIX + yy * W + xx;
      #pragma unroll
      for (int o = 0; o < OBJ; ++o) part[o] = my_w * mb[(size_t)o * NPIX];
    }
  }
  float inv = 1.f / sum;
  #pragma unroll
  for (int o = 0; o < OBJ; ++o) {
    float p = part[o];
    #pragma unroll
    for (int off = 32; off >= 1; off >>= 1) p += __shfl_xor(p, off, 64);
    if (lane == 0) out[(size_t)o * NPIX + wid] = p * inv;
  }
}

extern "C" void kernel_launch(void* const* d_in, const int* in_sizes, int n_in,
                              void* d_out, int out_size, void* d_ws, size_t ws_size,
                              hipStream_t stream) {
  const float* fq  = (const float*)d_in[0];
  const float* fm0 = (const float*)d_in[1];
  const float* fm1 = (const float*)d_in[2];
  const float* m0  = (const float*)d_in[3];
  const float* m1  = (const float*)d_in[4];
  float* out = (float*)d_out;

  char* ws = (char*)d_ws;
  float* mds  = (float*)ws;
  size_t mds_bytes = (size_t)2 * OBJ * NPIX * sizeof(float);
  float* corr = (float*)(ws + ((mds_bytes + 1023) / 1024) * 1024);

  k_downsample<<<(2 * OBJ * NPIX + 255) / 256, 256, 0, stream>>>(m0, m1, mds);

  k_corr<<<120 * 26, 64, 0, stream>>>(fq, fm0, fm1, corr);

  k_topk<<<NPIX / 4, 256, 0, stream>>>(corr, mds, out);
}